// Round 1
// baseline (3166.972 us; speedup 1.0000x reference)
//
#include <hip/hip_runtime.h>
#include <hip/hip_bf16.h>

// Problem constants
constexpr int B = 4, C = 128, T = 512, F = 128, H = 4, D = 64, DV = 32;
constexpr int E  = D * F;   // 8192
constexpr int EV = DV * F;  // 4096
constexpr float EPS = 1e-5f;

struct alignas(8) US4 { unsigned short x, y, z, w; };

__device__ __forceinline__ float bf2f(unsigned short u) {
  return __uint_as_float(((unsigned int)u) << 16);
}
__device__ __forceinline__ unsigned short f2bf(float f) {
  unsigned int b = __float_as_uint(f);
  unsigned int r = b + 0x7FFFu + ((b >> 16) & 1u);
  return (unsigned short)(r >> 16);
}

// ---------------------------------------------------------------------------
// Transpose small weight matrices: dst[m][c][r] = src[m][r][c]
__global__ void transpose_w(const float* __restrict__ src, float* __restrict__ dst,
                            int nmat, int R, int Cc) {
  int i = blockIdx.x * 256 + threadIdx.x;
  int per = R * Cc;
  if (i >= nmat * per) return;
  int m = i / per;
  int rem = i - m * per;
  int c = rem / R;
  int r = rem - c * R;
  dst[i] = src[(size_t)m * per + (size_t)r * Cc + c];
}

// ---------------------------------------------------------------------------
// Q/K/V projection + PReLU + LayerNorm over (d,f); writes bf16 in [B,H,T,DJ*F]
// grid: (b*T + t)*H + h, 8192 blocks; block: 128 threads (lane = f)
template <int DJ>
__global__ __launch_bounds__(128) void proj_kernel(
    const float* __restrict__ x, const float* __restrict__ WT,  // WT: [H][C][DJ]
    const float* __restrict__ bias, const float* __restrict__ alpha,
    const float* __restrict__ lw, const float* __restrict__ lb,
    unsigned short* __restrict__ outq) {
  int bx = blockIdx.x;
  int h = bx & (H - 1);
  int t = (bx >> 2) & (T - 1);
  int b = bx >> 11;
  int tid = threadIdx.x;

  float acc[DJ] = {};
  const float* xp = x + ((size_t)b * C * T + t) * F + tid;
  const float* wp = WT + (size_t)h * C * DJ;
  for (int c = 0; c < C; ++c) {
    float xv = xp[(size_t)c * T * F];
    const float* wc = wp + c * DJ;
#pragma unroll
    for (int d4 = 0; d4 < DJ / 4; ++d4) {
      float4 w = *reinterpret_cast<const float4*>(wc + d4 * 4);
      acc[d4 * 4 + 0] += w.x * xv;
      acc[d4 * 4 + 1] += w.y * xv;
      acc[d4 * 4 + 2] += w.z * xv;
      acc[d4 * 4 + 3] += w.w * xv;
    }
  }
  float aH = alpha[h];
  float s = 0.f, q2 = 0.f;
#pragma unroll
  for (int d = 0; d < DJ; ++d) {
    float v = acc[d] + bias[h * DJ + d];
    v = v >= 0.f ? v : aH * v;
    acc[d] = v;
    s += v;
    q2 += v * v;
  }
#pragma unroll
  for (int off = 32; off >= 1; off >>= 1) {
    s += __shfl_xor(s, off, 64);
    q2 += __shfl_xor(q2, off, 64);
  }
  __shared__ float red[4];
  int wv = tid >> 6;
  if ((tid & 63) == 0) { red[wv] = s; red[2 + wv] = q2; }
  __syncthreads();
  s = red[0] + red[1];
  q2 = red[2] + red[3];
  const float invN = 1.f / (float)(DJ * F);
  float mu = s * invN;
  float var = q2 * invN - mu * mu;
  float rstd = rsqrtf(var + EPS);

  unsigned short* ob = outq + (((size_t)b * H + h) * T + t) * (DJ * F) + tid;
  const float* lwp = lw + (size_t)h * DJ * F + tid;
  const float* lbp = lb + (size_t)h * DJ * F + tid;
#pragma unroll
  for (int d = 0; d < DJ; ++d) {
    float v = (acc[d] - mu) * rstd * lwp[(size_t)d * F] + lbp[(size_t)d * F];
    ob[(size_t)d * F] = f2bf(v);
  }
}

// ---------------------------------------------------------------------------
// Logits: L[bh,t,s] = scale * dot(qf[bh,t,:], kf[bh,s,:]); 64x64 tile per block
// grid: 16 bh * 64 tiles = 1024 blocks; block 256 threads (16x16, 4x4 outputs)
__global__ __launch_bounds__(256) void logits_kernel(
    const unsigned short* __restrict__ qf, const unsigned short* __restrict__ kf,
    float* __restrict__ attnL) {
  __shared__ float qs[64][68];
  __shared__ float ks[64][68];
  int bx = blockIdx.x;
  int bh = bx >> 6;
  int tl = bx & 63;
  int ti = (tl >> 3) << 6;
  int si = (tl & 7) << 6;
  int tid = threadIdx.x;
  int ty = tid >> 4, tx = tid & 15;
  float acc[4][4] = {};
  const unsigned short* qb = qf + ((size_t)bh * T + ti) * E;
  const unsigned short* kb = kf + ((size_t)bh * T + si) * E;

  for (int k0 = 0; k0 < E; k0 += 64) {
#pragma unroll
    for (int j = 0; j < 4; ++j) {
      int e = (j << 10) + (tid << 2);
      int r = e >> 6;
      int kk = e & 63;
      US4 uq = *reinterpret_cast<const US4*>(qb + (size_t)r * E + k0 + kk);
      qs[kk + 0][r] = bf2f(uq.x);
      qs[kk + 1][r] = bf2f(uq.y);
      qs[kk + 2][r] = bf2f(uq.z);
      qs[kk + 3][r] = bf2f(uq.w);
      US4 uk = *reinterpret_cast<const US4*>(kb + (size_t)r * E + k0 + kk);
      ks[kk + 0][r] = bf2f(uk.x);
      ks[kk + 1][r] = bf2f(uk.y);
      ks[kk + 2][r] = bf2f(uk.z);
      ks[kk + 3][r] = bf2f(uk.w);
    }
    __syncthreads();
#pragma unroll 8
    for (int kk = 0; kk < 64; ++kk) {
      float4 qa = *reinterpret_cast<const float4*>(&qs[kk][ty << 2]);
      float4 kv = *reinterpret_cast<const float4*>(&ks[kk][tx << 2]);
      acc[0][0] += qa.x * kv.x; acc[0][1] += qa.x * kv.y; acc[0][2] += qa.x * kv.z; acc[0][3] += qa.x * kv.w;
      acc[1][0] += qa.y * kv.x; acc[1][1] += qa.y * kv.y; acc[1][2] += qa.y * kv.z; acc[1][3] += qa.y * kv.w;
      acc[2][0] += qa.z * kv.x; acc[2][1] += qa.z * kv.y; acc[2][2] += qa.z * kv.z; acc[2][3] += qa.z * kv.w;
      acc[3][0] += qa.w * kv.x; acc[3][1] += qa.w * kv.y; acc[3][2] += qa.w * kv.z; acc[3][3] += qa.w * kv.w;
    }
    __syncthreads();
  }
  const float scale = 0.011048543456039806f;  // 1/sqrt(8192)
#pragma unroll
  for (int i = 0; i < 4; ++i) {
    float4 o;
    o.x = acc[i][0] * scale;
    o.y = acc[i][1] * scale;
    o.z = acc[i][2] * scale;
    o.w = acc[i][3] * scale;
    *reinterpret_cast<float4*>(
        &attnL[((size_t)bh * T + ti + (ty << 2) + i) * T + si + (tx << 2)]) = o;
  }
}

// ---------------------------------------------------------------------------
// Softmax in-place over last dim (512); one wave per row
__global__ __launch_bounds__(64) void softmax_kernel(float* __restrict__ a) {
  float* p = a + (size_t)blockIdx.x * T;
  int tid = threadIdx.x;
  float4 v0 = *reinterpret_cast<float4*>(p + tid * 8);
  float4 v1 = *reinterpret_cast<float4*>(p + tid * 8 + 4);
  float mx = fmaxf(fmaxf(fmaxf(v0.x, v0.y), fmaxf(v0.z, v0.w)),
                   fmaxf(fmaxf(v1.x, v1.y), fmaxf(v1.z, v1.w)));
#pragma unroll
  for (int off = 32; off >= 1; off >>= 1) mx = fmaxf(mx, __shfl_xor(mx, off, 64));
  v0.x = __expf(v0.x - mx); v0.y = __expf(v0.y - mx);
  v0.z = __expf(v0.z - mx); v0.w = __expf(v0.w - mx);
  v1.x = __expf(v1.x - mx); v1.y = __expf(v1.y - mx);
  v1.z = __expf(v1.z - mx); v1.w = __expf(v1.w - mx);
  float sm = v0.x + v0.y + v0.z + v0.w + v1.x + v1.y + v1.z + v1.w;
#pragma unroll
  for (int off = 32; off >= 1; off >>= 1) sm += __shfl_xor(sm, off, 64);
  float r = 1.0f / sm;
  v0.x *= r; v0.y *= r; v0.z *= r; v0.w *= r;
  v1.x *= r; v1.y *= r; v1.z *= r; v1.w *= r;
  *reinterpret_cast<float4*>(p + tid * 8) = v0;
  *reinterpret_cast<float4*>(p + tid * 8 + 4) = v1;
}

// ---------------------------------------------------------------------------
// PV: pv[bh,t,e] = sum_s attn[bh,t,s] * vf[bh,s,e]
// grid: bh(16) x ttile(16) x echunk(8) = 2048 blocks; 256 threads
// block covers 32 t-rows x 512 e-cols; thread owns e0=2*tid, e0+1 pair
__global__ __launch_bounds__(256) void pv_kernel(
    const float* __restrict__ attn, const unsigned short* __restrict__ vf,
    unsigned short* __restrict__ pv) {
  __shared__ float As[512][32];  // [s][t-row], 64 KB
  int bx = blockIdx.x;
  int ec = bx & 7;
  int tt = (bx >> 3) & 15;
  int bh = bx >> 7;
  int tid = threadIdx.x;

  const float* ab = attn + ((size_t)bh * T + tt * 32) * T;
#pragma unroll
  for (int j = 0; j < 16; ++j) {
    int e = (j << 10) + (tid << 2);
    int r = e >> 9;
    int s0 = e & 511;
    float4 av = *reinterpret_cast<const float4*>(ab + (size_t)r * T + s0);
    As[s0 + 0][r] = av.x;
    As[s0 + 1][r] = av.y;
    As[s0 + 2][r] = av.z;
    As[s0 + 3][r] = av.w;
  }
  __syncthreads();

  int e0 = ec * 512 + tid * 2;
  const unsigned short* vb = vf + (size_t)bh * T * EV + e0;
  float acc0[32] = {}, acc1[32] = {};
  for (int s = 0; s < T; ++s) {
    unsigned int u = *reinterpret_cast<const unsigned int*>(vb + (size_t)s * EV);
    float v0 = bf2f((unsigned short)(u & 0xFFFFu));
    float v1 = bf2f((unsigned short)(u >> 16));
#pragma unroll
    for (int m = 0; m < 8; ++m) {
      float4 a = *reinterpret_cast<const float4*>(&As[s][m * 4]);
      acc0[m * 4 + 0] += a.x * v0; acc1[m * 4 + 0] += a.x * v1;
      acc0[m * 4 + 1] += a.y * v0; acc1[m * 4 + 1] += a.y * v1;
      acc0[m * 4 + 2] += a.z * v0; acc1[m * 4 + 2] += a.z * v1;
      acc0[m * 4 + 3] += a.w * v0; acc1[m * 4 + 3] += a.w * v1;
    }
  }
  unsigned short* ob = pv + ((size_t)bh * T + tt * 32) * EV + e0;
#pragma unroll
  for (int r = 0; r < 32; ++r) {
    unsigned int w = (unsigned int)f2bf(acc0[r]) | ((unsigned int)f2bf(acc1[r]) << 16);
    *reinterpret_cast<unsigned int*>(ob + (size_t)r * EV) = w;
  }
}

// ---------------------------------------------------------------------------
// Output proj + PReLU + LayerNorm(C,F) + affine + residual
// grid: b*T + t (2048 blocks); 256 threads: f = tid&127, half = tid>>7 (d range)
__global__ __launch_bounds__(256) void outproj_kernel(
    const unsigned short* __restrict__ pv, const float* __restrict__ WoT,  // [c][d]
    const float* __restrict__ bo, const float* __restrict__ ao,
    const float* __restrict__ lwo, const float* __restrict__ lbo,
    const float* __restrict__ x, float* __restrict__ outp) {
  int bx = blockIdx.x;
  int t = bx & (T - 1);
  int b = bx >> 9;
  int tid = threadIdx.x;
  int f = tid & (F - 1);
  int half = tid >> 7;
  int d0 = half * 64;

  float acc[64] = {};
  for (int c = 0; c < C; ++c) {
    // r[b,c,t,f] = pv[b, h=c>>5, t, (c&31)*F + f]
    float rv = bf2f(pv[(((size_t)b * H + (c >> 5)) * T + t) * EV + (c & 31) * F + f]);
    const float* wp = WoT + c * C + d0;
#pragma unroll
    for (int d4 = 0; d4 < 16; ++d4) {
      float4 w = *reinterpret_cast<const float4*>(wp + d4 * 4);
      acc[d4 * 4 + 0] += w.x * rv;
      acc[d4 * 4 + 1] += w.y * rv;
      acc[d4 * 4 + 2] += w.z * rv;
      acc[d4 * 4 + 3] += w.w * rv;
    }
  }
  float aO = ao[0];
  float s = 0.f, q2 = 0.f;
#pragma unroll
  for (int dd = 0; dd < 64; ++dd) {
    float v = acc[dd] + bo[d0 + dd];
    v = v >= 0.f ? v : aO * v;
    acc[dd] = v;
    s += v;
    q2 += v * v;
  }
#pragma unroll
  for (int off = 32; off >= 1; off >>= 1) {
    s += __shfl_xor(s, off, 64);
    q2 += __shfl_xor(q2, off, 64);
  }
  __shared__ float red[8];
  int wv = tid >> 6;
  if ((tid & 63) == 0) { red[wv] = s; red[4 + wv] = q2; }
  __syncthreads();
  s = red[0] + red[1] + red[2] + red[3];
  q2 = red[4] + red[5] + red[6] + red[7];
  const float invN = 1.f / 16384.f;
  float mu = s * invN;
  float var = q2 * invN - mu * mu;
  float rstd = rsqrtf(var + EPS);
#pragma unroll
  for (int dd = 0; dd < 64; ++dd) {
    int d = d0 + dd;
    float v = (acc[dd] - mu) * rstd * lwo[d * F + f] + lbo[d * F + f];
    size_t xi = (((size_t)b * C + d) * T + t) * F + f;
    outp[xi] = v + x[xi];
  }
}

// ---------------------------------------------------------------------------
extern "C" void kernel_launch(void* const* d_in, const int* in_sizes, int n_in,
                              void* d_out, int out_size, void* d_ws, size_t ws_size,
                              hipStream_t stream) {
  const float* x   = (const float*)d_in[0];
  const float* Wq  = (const float*)d_in[1];
  const float* bq  = (const float*)d_in[2];
  const float* aq  = (const float*)d_in[3];
  const float* lwq = (const float*)d_in[4];
  const float* lbq = (const float*)d_in[5];
  const float* Wk  = (const float*)d_in[6];
  const float* bk_ = (const float*)d_in[7];
  const float* ak  = (const float*)d_in[8];
  const float* lwk = (const float*)d_in[9];
  const float* lbk = (const float*)d_in[10];
  const float* Wv  = (const float*)d_in[11];
  const float* bv  = (const float*)d_in[12];
  const float* av  = (const float*)d_in[13];
  const float* lwv = (const float*)d_in[14];
  const float* lbv = (const float*)d_in[15];
  const float* Wo  = (const float*)d_in[16];
  const float* bo  = (const float*)d_in[17];
  const float* ao  = (const float*)d_in[18];
  const float* lwo = (const float*)d_in[19];
  const float* lbo = (const float*)d_in[20];
  float* outp = (float*)d_out;

  char* ws = (char*)d_ws;
  unsigned short* qfp = (unsigned short*)(ws);                 // 134,217,728 B
  unsigned short* kfp = (unsigned short*)(ws + 134217728ull);  // 134,217,728 B
  unsigned short* vfp = (unsigned short*)(ws + 268435456ull);  //  67,108,864 B
  float*          atn = (float*)(ws + 335544320ull);           //  16,777,216 B
  unsigned short* pvp = (unsigned short*)(ws + 352321536ull);  //  67,108,864 B
  float*          WoT = (float*)(ws + 419430400ull);           //      65,536 B
  float*          WqT = (float*)(ws + 419495936ull);           //     131,072 B
  float*          WkT = (float*)(ws + 419627008ull);           //     131,072 B
  float*          WvT = (float*)(ws + 419758080ull);           //      65,536 B

  transpose_w<<<128, 256, 0, stream>>>(Wq, WqT, 4, 64, 128);
  transpose_w<<<128, 256, 0, stream>>>(Wk, WkT, 4, 64, 128);
  transpose_w<<<64, 256, 0, stream>>>(Wv, WvT, 4, 32, 128);
  transpose_w<<<64, 256, 0, stream>>>(Wo, WoT, 1, 128, 128);

  proj_kernel<64><<<8192, 128, 0, stream>>>(x, WqT, bq, aq, lwq, lbq, qfp);
  proj_kernel<64><<<8192, 128, 0, stream>>>(x, WkT, bk_, ak, lwk, lbk, kfp);
  proj_kernel<32><<<8192, 128, 0, stream>>>(x, WvT, bv, av, lwv, lbv, vfp);

  logits_kernel<<<1024, 256, 0, stream>>>(qfp, kfp, atn);
  softmax_kernel<<<8192, 64, 0, stream>>>(atn);
  pv_kernel<<<2048, 256, 0, stream>>>(atn, vfp, pvp);
  outproj_kernel<<<2048, 256, 0, stream>>>(pvp, WoT, bo, ao, lwo, lbo, x, outp);
}

// Round 2
// 1609.317 us; speedup vs baseline: 1.9679x; 1.9679x over previous
//
#include <hip/hip_runtime.h>
#include <hip/hip_bf16.h>

// Problem constants
constexpr int B = 4, C = 128, T = 512, F = 128, H = 4, D = 64, DV = 32;
constexpr int E  = D * F;   // 8192
constexpr int EV = DV * F;  // 4096
constexpr float EPS = 1e-5f;

struct alignas(8) US4 { unsigned short x, y, z, w; };

typedef __attribute__((ext_vector_type(4))) float f32x4;
typedef __attribute__((ext_vector_type(8))) short bf16x8;

__device__ __forceinline__ float bf2f(unsigned short u) {
  return __uint_as_float(((unsigned int)u) << 16);
}
__device__ __forceinline__ unsigned short f2bf(float f) {
  unsigned int b = __float_as_uint(f);
  unsigned int r = b + 0x7FFFu + ((b >> 16) & 1u);
  return (unsigned short)(r >> 16);
}

__device__ __forceinline__ void gl_lds16(const unsigned short* g, unsigned short* l) {
  __builtin_amdgcn_global_load_lds(
      (const __attribute__((address_space(1))) unsigned int*)(g),
      (__attribute__((address_space(3))) unsigned int*)(l), 16, 0, 0);
}

// ---------------------------------------------------------------------------
// Transpose small weight matrices: dst[m][c][r] = src[m][r][c]
__global__ void transpose_w(const float* __restrict__ src, float* __restrict__ dst,
                            int nmat, int R, int Cc) {
  int i = blockIdx.x * 256 + threadIdx.x;
  int per = R * Cc;
  if (i >= nmat * per) return;
  int m = i / per;
  int rem = i - m * per;
  int c = rem / R;
  int r = rem - c * R;
  dst[i] = src[(size_t)m * per + (size_t)r * Cc + c];
}

// ---------------------------------------------------------------------------
// Q/K/V projection + PReLU + LayerNorm over (d,f); writes bf16 in [B,H,T,DJ*F]
template <int DJ>
__global__ __launch_bounds__(128) void proj_kernel(
    const float* __restrict__ x, const float* __restrict__ WT,  // WT: [H][C][DJ]
    const float* __restrict__ bias, const float* __restrict__ alpha,
    const float* __restrict__ lw, const float* __restrict__ lb,
    unsigned short* __restrict__ outq) {
  int bx = blockIdx.x;
  int h = bx & (H - 1);
  int t = (bx >> 2) & (T - 1);
  int b = bx >> 11;
  int tid = threadIdx.x;

  float acc[DJ] = {};
  const float* xp = x + ((size_t)b * C * T + t) * F + tid;
  const float* wp = WT + (size_t)h * C * DJ;
  for (int c = 0; c < C; ++c) {
    float xv = xp[(size_t)c * T * F];
    const float* wc = wp + c * DJ;
#pragma unroll
    for (int d4 = 0; d4 < DJ / 4; ++d4) {
      float4 w = *reinterpret_cast<const float4*>(wc + d4 * 4);
      acc[d4 * 4 + 0] += w.x * xv;
      acc[d4 * 4 + 1] += w.y * xv;
      acc[d4 * 4 + 2] += w.z * xv;
      acc[d4 * 4 + 3] += w.w * xv;
    }
  }
  float aH = alpha[h];
  float s = 0.f, q2 = 0.f;
#pragma unroll
  for (int d = 0; d < DJ; ++d) {
    float v = acc[d] + bias[h * DJ + d];
    v = v >= 0.f ? v : aH * v;
    acc[d] = v;
    s += v;
    q2 += v * v;
  }
#pragma unroll
  for (int off = 32; off >= 1; off >>= 1) {
    s += __shfl_xor(s, off, 64);
    q2 += __shfl_xor(q2, off, 64);
  }
  __shared__ float red[4];
  int wv = tid >> 6;
  if ((tid & 63) == 0) { red[wv] = s; red[2 + wv] = q2; }
  __syncthreads();
  s = red[0] + red[1];
  q2 = red[2] + red[3];
  const float invN = 1.f / (float)(DJ * F);
  float mu = s * invN;
  float var = q2 * invN - mu * mu;
  float rstd = rsqrtf(var + EPS);

  unsigned short* ob = outq + (((size_t)b * H + h) * T + t) * (DJ * F) + tid;
  const float* lwp = lw + (size_t)h * DJ * F + tid;
  const float* lbp = lb + (size_t)h * DJ * F + tid;
#pragma unroll
  for (int d = 0; d < DJ; ++d) {
    float v = (acc[d] - mu) * rstd * lwp[(size_t)d * F] + lbp[(size_t)d * F];
    ob[(size_t)d * F] = f2bf(v);
  }
}

// ---------------------------------------------------------------------------
// MFMA GEMM, A·B^T form: Out[bh][m][n] = scale * sum_k A[bh][m][k]*Bm[bh][n][k]
// Tile 128x128, BK=64; 256 threads = 4 waves, each wave a 64x64 sub-tile.
// m97 structure: global_load_lds width-16 staging, linear LDS, 2-barrier loop.
template <bool OUT_BF16>
__global__ __launch_bounds__(256) void gemm_bt_kernel(
    const unsigned short* __restrict__ A,   // [nb][M][K] bf16
    const unsigned short* __restrict__ Bm,  // [nb][N][K] bf16
    void* __restrict__ Out,                 // [nb][M][N]
    int M, int N, int K, float scale, int tiles_m, int tiles_n) {
  __shared__ alignas(16) unsigned short As[128 * 64];
  __shared__ alignas(16) unsigned short Bs[128 * 64];

  // XCD-chunk swizzle: physical p -> virtual v so each XCD gets a contiguous chunk
  int p = blockIdx.x;
  int cpx = gridDim.x >> 3;         // grid divisible by 8 for both uses
  int v = (p & 7) * cpx + (p >> 3);
  int tpb = tiles_m * tiles_n;
  int bh = v / tpb;
  int tl = v - bh * tpb;
  int tm = tl / tiles_n;
  int tn = tl - tm * tiles_n;

  int tid = threadIdx.x;
  int w = tid >> 6, lane = tid & 63;
  int wr = w >> 1, wc = w & 1;      // wave position in 2x2 grid of 64x64 tiles
  int lr = lane & 15;               // row-in-16 for A/B frags, col for C
  int kg = lane >> 4;               // k-group 0..3

  const unsigned short* Ab = A + ((size_t)bh * M + tm * 128) * K;
  const unsigned short* Bb = Bm + ((size_t)bh * N + tn * 128) * K;

  f32x4 acc[4][4] = {};

  for (int k0 = 0; k0 < K; k0 += 64) {
#pragma unroll
    for (int j = 0; j < 4; ++j) {
      int ch = j * 256 + tid;             // 0..1023 16B-chunks
      int r = ch >> 3;                    // row 0..127
      int c = (ch & 7) * 8;               // k-col within 64
      gl_lds16(Ab + (size_t)r * K + k0 + c, &As[ch * 8]);
      gl_lds16(Bb + (size_t)r * K + k0 + c, &Bs[ch * 8]);
    }
    __syncthreads();
#pragma unroll
    for (int ks = 0; ks < 2; ++ks) {
      bf16x8 af[4], bf[4];
#pragma unroll
      for (int m = 0; m < 4; ++m)
        af[m] = *reinterpret_cast<const bf16x8*>(
            &As[(wr * 64 + m * 16 + lr) * 64 + ks * 32 + kg * 8]);
#pragma unroll
      for (int n = 0; n < 4; ++n)
        bf[n] = *reinterpret_cast<const bf16x8*>(
            &Bs[(wc * 64 + n * 16 + lr) * 64 + ks * 32 + kg * 8]);
#pragma unroll
      for (int m = 0; m < 4; ++m)
#pragma unroll
        for (int n = 0; n < 4; ++n)
          acc[m][n] = __builtin_amdgcn_mfma_f32_16x16x32_bf16(af[m], bf[n], acc[m][n], 0, 0, 0);
    }
    __syncthreads();
  }

  // C/D layout (m89/m91): col = lane&15, row = (lane>>4)*4 + reg
  int orow = tm * 128 + wr * 64 + kg * 4;
  int ocol = tn * 128 + wc * 64 + lr;
  if constexpr (OUT_BF16) {
    unsigned short* O = (unsigned short*)Out + (size_t)bh * M * N;
#pragma unroll
    for (int m = 0; m < 4; ++m)
#pragma unroll
      for (int j = 0; j < 4; ++j) {
        size_t base = (size_t)(orow + m * 16 + j) * N + ocol;
#pragma unroll
        for (int n = 0; n < 4; ++n)
          O[base + n * 16] = f2bf(acc[m][n][j] * scale);
      }
  } else {
    float* O = (float*)Out + (size_t)bh * M * N;
#pragma unroll
    for (int m = 0; m < 4; ++m)
#pragma unroll
      for (int j = 0; j < 4; ++j) {
        size_t base = (size_t)(orow + m * 16 + j) * N + ocol;
#pragma unroll
        for (int n = 0; n < 4; ++n)
          O[base + n * 16] = acc[m][n][j] * scale;
      }
  }
}

// ---------------------------------------------------------------------------
// Transpose vf [bh][T][EV] -> vfT [bh][EV][T] (bf16), 64x64 tiles
__global__ __launch_bounds__(256) void transpose_v_kernel(
    const unsigned short* __restrict__ src, unsigned short* __restrict__ dst) {
  __shared__ unsigned short tile[64][72];
  int bx = blockIdx.x;
  int et = bx & 63;
  int tt = (bx >> 6) & 7;
  int bh = bx >> 9;
  const unsigned short* sb = src + ((size_t)bh * T + tt * 64) * EV + et * 64;
#pragma unroll
  for (int j = 0; j < 2; ++j) {
    int ch = j * 256 + threadIdx.x;  // 0..511
    int r = ch >> 3;                 // t-row 0..63
    int c8 = ch & 7;                 // 8-elem group
    uint4 u = *reinterpret_cast<const uint4*>(sb + (size_t)r * EV + c8 * 8);
    *reinterpret_cast<uint4*>(&tile[r][c8 * 8]) = u;
  }
  __syncthreads();
  unsigned short* db = dst + ((size_t)bh * EV + et * 64) * T + tt * 64;
#pragma unroll
  for (int j = 0; j < 2; ++j) {
    int ch = j * 256 + threadIdx.x;
    int r = ch >> 3;                 // e-row 0..63
    int c8 = ch & 7;
    unsigned short o[8];
#pragma unroll
    for (int i = 0; i < 8; ++i) o[i] = tile[c8 * 8 + i][r];
    *reinterpret_cast<uint4*>(db + (size_t)r * T + c8 * 8) =
        *reinterpret_cast<const uint4*>(o);
  }
}

// ---------------------------------------------------------------------------
// Softmax over last dim (512); reads fp32 logits, writes bf16 probs
__global__ __launch_bounds__(64) void softmax_kernel(const float* __restrict__ a,
                                                     unsigned short* __restrict__ ob) {
  const float* pr = a + (size_t)blockIdx.x * T;
  int tid = threadIdx.x;
  float4 v0 = *reinterpret_cast<const float4*>(pr + tid * 8);
  float4 v1 = *reinterpret_cast<const float4*>(pr + tid * 8 + 4);
  float mx = fmaxf(fmaxf(fmaxf(v0.x, v0.y), fmaxf(v0.z, v0.w)),
                   fmaxf(fmaxf(v1.x, v1.y), fmaxf(v1.z, v1.w)));
#pragma unroll
  for (int off = 32; off >= 1; off >>= 1) mx = fmaxf(mx, __shfl_xor(mx, off, 64));
  v0.x = __expf(v0.x - mx); v0.y = __expf(v0.y - mx);
  v0.z = __expf(v0.z - mx); v0.w = __expf(v0.w - mx);
  v1.x = __expf(v1.x - mx); v1.y = __expf(v1.y - mx);
  v1.z = __expf(v1.z - mx); v1.w = __expf(v1.w - mx);
  float sm = v0.x + v0.y + v0.z + v0.w + v1.x + v1.y + v1.z + v1.w;
#pragma unroll
  for (int off = 32; off >= 1; off >>= 1) sm += __shfl_xor(sm, off, 64);
  float r = 1.0f / sm;
  uint4 o;
  o.x = (unsigned int)f2bf(v0.x * r) | ((unsigned int)f2bf(v0.y * r) << 16);
  o.y = (unsigned int)f2bf(v0.z * r) | ((unsigned int)f2bf(v0.w * r) << 16);
  o.z = (unsigned int)f2bf(v1.x * r) | ((unsigned int)f2bf(v1.y * r) << 16);
  o.w = (unsigned int)f2bf(v1.z * r) | ((unsigned int)f2bf(v1.w * r) << 16);
  *reinterpret_cast<uint4*>(ob + (size_t)blockIdx.x * T + tid * 8) = o;
}

// ---------------------------------------------------------------------------
// Output proj + PReLU + LayerNorm(C,F) + affine + residual
__global__ __launch_bounds__(256) void outproj_kernel(
    const unsigned short* __restrict__ pv, const float* __restrict__ WoT,  // [c][d]
    const float* __restrict__ bo, const float* __restrict__ ao,
    const float* __restrict__ lwo, const float* __restrict__ lbo,
    const float* __restrict__ x, float* __restrict__ outp) {
  int bx = blockIdx.x;
  int t = bx & (T - 1);
  int b = bx >> 9;
  int tid = threadIdx.x;
  int f = tid & (F - 1);
  int half = tid >> 7;
  int d0 = half * 64;

  float acc[64] = {};
  for (int c = 0; c < C; ++c) {
    float rv = bf2f(pv[(((size_t)b * H + (c >> 5)) * T + t) * EV + (c & 31) * F + f]);
    const float* wp = WoT + c * C + d0;
#pragma unroll
    for (int d4 = 0; d4 < 16; ++d4) {
      float4 w = *reinterpret_cast<const float4*>(wp + d4 * 4);
      acc[d4 * 4 + 0] += w.x * rv;
      acc[d4 * 4 + 1] += w.y * rv;
      acc[d4 * 4 + 2] += w.z * rv;
      acc[d4 * 4 + 3] += w.w * rv;
    }
  }
  float aO = ao[0];
  float s = 0.f, q2 = 0.f;
#pragma unroll
  for (int dd = 0; dd < 64; ++dd) {
    float v2 = acc[dd] + bo[d0 + dd];
    v2 = v2 >= 0.f ? v2 : aO * v2;
    acc[dd] = v2;
    s += v2;
    q2 += v2 * v2;
  }
#pragma unroll
  for (int off = 32; off >= 1; off >>= 1) {
    s += __shfl_xor(s, off, 64);
    q2 += __shfl_xor(q2, off, 64);
  }
  __shared__ float red[8];
  int wv = tid >> 6;
  if ((tid & 63) == 0) { red[wv] = s; red[4 + wv] = q2; }
  __syncthreads();
  s = red[0] + red[1] + red[2] + red[3];
  q2 = red[4] + red[5] + red[6] + red[7];
  const float invN = 1.f / 16384.f;
  float mu = s * invN;
  float var = q2 * invN - mu * mu;
  float rstd = rsqrtf(var + EPS);
#pragma unroll
  for (int dd = 0; dd < 64; ++dd) {
    int d = d0 + dd;
    float v2 = (acc[dd] - mu) * rstd * lwo[d * F + f] + lbo[d * F + f];
    size_t xi = (((size_t)b * C + d) * T + t) * F + f;
    outp[xi] = v2 + x[xi];
  }
}

// ---------------------------------------------------------------------------
extern "C" void kernel_launch(void* const* d_in, const int* in_sizes, int n_in,
                              void* d_out, int out_size, void* d_ws, size_t ws_size,
                              hipStream_t stream) {
  const float* x   = (const float*)d_in[0];
  const float* Wq  = (const float*)d_in[1];
  const float* bq  = (const float*)d_in[2];
  const float* aq  = (const float*)d_in[3];
  const float* lwq = (const float*)d_in[4];
  const float* lbq = (const float*)d_in[5];
  const float* Wk  = (const float*)d_in[6];
  const float* bk_ = (const float*)d_in[7];
  const float* ak  = (const float*)d_in[8];
  const float* lwk = (const float*)d_in[9];
  const float* lbk = (const float*)d_in[10];
  const float* Wv  = (const float*)d_in[11];
  const float* bv  = (const float*)d_in[12];
  const float* av  = (const float*)d_in[13];
  const float* lwv = (const float*)d_in[14];
  const float* lbv = (const float*)d_in[15];
  const float* Wo  = (const float*)d_in[16];
  const float* bo  = (const float*)d_in[17];
  const float* ao  = (const float*)d_in[18];
  const float* lwo = (const float*)d_in[19];
  const float* lbo = (const float*)d_in[20];
  float* outp = (float*)d_out;

  char* ws = (char*)d_ws;
  // Phase 1 regions
  unsigned short* qfp = (unsigned short*)(ws);                 // 128 MB
  unsigned short* kfp = (unsigned short*)(ws + 134217728ull);  // 128 MB
  unsigned short* vfp = (unsigned short*)(ws + 268435456ull);  //  64 MB
  float*          atn = (float*)(ws + 335544320ull);           //  16 MB fp32 logits
  float*          WoT = (float*)(ws + 352321536ull);           //  64 KB
  float*          WqT = (float*)(ws + 352387072ull);           // 128 KB
  float*          WkT = (float*)(ws + 352518144ull);           // 128 KB
  float*          WvT = (float*)(ws + 352649216ull);           //  64 KB
  // Phase 2 regions (reuse dead phase-1 space)
  unsigned short* atnb = (unsigned short*)(ws);                //  8 MB (ex-qf)
  unsigned short* vfT  = (unsigned short*)(ws + 134217728ull); // 64 MB (ex-kf)
  unsigned short* pvp  = (unsigned short*)(ws + 268435456ull); // 64 MB (ex-vf)

  transpose_w<<<128, 256, 0, stream>>>(Wq, WqT, 4, 64, 128);
  transpose_w<<<128, 256, 0, stream>>>(Wk, WkT, 4, 64, 128);
  transpose_w<<<64, 256, 0, stream>>>(Wv, WvT, 4, 32, 128);
  transpose_w<<<64, 256, 0, stream>>>(Wo, WoT, 1, 128, 128);

  proj_kernel<64><<<8192, 128, 0, stream>>>(x, WqT, bq, aq, lwq, lbq, qfp);
  proj_kernel<64><<<8192, 128, 0, stream>>>(x, WkT, bk_, ak, lwk, lbk, kfp);
  proj_kernel<32><<<8192, 128, 0, stream>>>(x, WvT, bv, av, lwv, lbv, vfp);

  // logits: S = scale * Q K^T   (M=N=512, K=8192), fp32 out
  gemm_bt_kernel<false><<<256, 256, 0, stream>>>(
      qfp, kfp, atn, 512, 512, 8192, 0.011048543456039806f, 4, 4);

  // vf [bh][T][EV] -> vfT [bh][EV][T]   (qf/kf now dead)
  transpose_v_kernel<<<8192, 256, 0, stream>>>(vfp, vfT);

  // softmax fp32 -> bf16 probs (into ex-qf space)
  softmax_kernel<<<8192, 64, 0, stream>>>(atn, atnb);

  // PV: O = P V   via A·B^T with B = vfT  (M=512, N=4096, K=512), bf16 out
  gemm_bt_kernel<true><<<2048, 256, 0, stream>>>(
      atnb, vfT, pvp, 512, 4096, 512, 1.0f, 4, 32);

  outproj_kernel<<<2048, 256, 0, stream>>>(pvp, WoT, bo, ao, lwo, lbo, x, outp);
}

// Round 3
// 679.609 us; speedup vs baseline: 4.6600x; 2.3680x over previous
//
#include <hip/hip_runtime.h>
#include <hip/hip_bf16.h>

// Problem constants
constexpr int B = 4, C = 128, T = 512, F = 128, H = 4, D = 64, DV = 32;
constexpr int E  = D * F;   // 8192
constexpr int EV = DV * F;  // 4096
constexpr float EPS = 1e-5f;

typedef __attribute__((ext_vector_type(4))) float f32x4;
typedef __attribute__((ext_vector_type(8))) short bf16x8;

__device__ __forceinline__ float bf2f(unsigned short u) {
  return __uint_as_float(((unsigned int)u) << 16);
}
__device__ __forceinline__ unsigned short f2bf(float f) {
  unsigned int b = __float_as_uint(f);
  unsigned int r = b + 0x7FFFu + ((b >> 16) & 1u);
  return (unsigned short)(r >> 16);
}

__device__ __forceinline__ void gl_lds16(const unsigned short* g, unsigned short* l) {
  __builtin_amdgcn_global_load_lds(
      (const __attribute__((address_space(1))) unsigned int*)(g),
      (__attribute__((address_space(3))) unsigned int*)(l), 16, 0, 0);
}

// ---------------------------------------------------------------------------
// Pack weights: Wall[640][128] bf16 (q,k,v rows), Wo2[128][128] bf16,
// ball/aall[640], lwall/lball[640][128] fp32 concat
__global__ __launch_bounds__(256) void prep_kernel(
    const float* __restrict__ Wq, const float* __restrict__ Wk,
    const float* __restrict__ Wv, const float* __restrict__ Wo,
    const float* __restrict__ bq, const float* __restrict__ bk,
    const float* __restrict__ bv, const float* __restrict__ aq,
    const float* __restrict__ ak, const float* __restrict__ av,
    const float* __restrict__ lwq, const float* __restrict__ lwk,
    const float* __restrict__ lwv, const float* __restrict__ lbq,
    const float* __restrict__ lbk, const float* __restrict__ lbv,
    unsigned short* __restrict__ Wall, unsigned short* __restrict__ Wo2,
    float* __restrict__ ball, float* __restrict__ aall,
    float* __restrict__ lwall, float* __restrict__ lball) {
  int i = blockIdx.x * 256 + threadIdx.x;
  if (i < 81920) {
    float w = (i < 32768) ? Wq[i] : (i < 65536) ? Wk[i - 32768] : Wv[i - 65536];
    Wall[i] = f2bf(w);
    float lw = (i < 32768) ? lwq[i] : (i < 65536) ? lwk[i - 32768] : lwv[i - 65536];
    lwall[i] = lw;
    float lb = (i < 32768) ? lbq[i] : (i < 65536) ? lbk[i - 32768] : lbv[i - 65536];
    lball[i] = lb;
  }
  if (i < 16384) Wo2[i] = f2bf(Wo[i]);
  if (i < 640) {
    ball[i] = (i < 256) ? bq[i] : (i < 512) ? bk[i - 256] : bv[i - 512];
    aall[i] = (i < 256) ? aq[i >> 6] : (i < 512) ? ak[(i - 256) >> 6] : av[(i - 512) >> 5];
  }
}

// ---------------------------------------------------------------------------
// xT[b][(t*128+f)][c] bf16  <-  x[b][c][t][f] fp32.  One block per (b,t).
__global__ __launch_bounds__(256) void xT_kernel(const float* __restrict__ x,
                                                 unsigned short* __restrict__ xT) {
  __shared__ unsigned short tile[128][136];  // [c][f]
  int bx = blockIdx.x;
  int t = bx & 511;
  int b = bx >> 9;
  int tid = threadIdx.x;
#pragma unroll
  for (int j = 0; j < 16; ++j) {
    int ch = j * 256 + tid;       // 4096 float4 chunks
    int c = ch >> 5;
    int fc = ch & 31;
    float4 v = *reinterpret_cast<const float4*>(
        x + (((size_t)b * C + c) * T + t) * F + fc * 4);
    unsigned short o[4] = {f2bf(v.x), f2bf(v.y), f2bf(v.z), f2bf(v.w)};
    *reinterpret_cast<ushort4*>(&tile[c][fc * 4]) = *reinterpret_cast<const ushort4*>(o);
  }
  __syncthreads();
  int f = tid >> 1, half = tid & 1;
  unsigned short* dst = xT + ((size_t)b * 65536 + (size_t)t * 128 + f) * 128 + half * 64;
#pragma unroll
  for (int g8 = 0; g8 < 8; ++g8) {
    unsigned short o[8];
#pragma unroll
    for (int kk = 0; kk < 8; ++kk) o[kk] = tile[half * 64 + g8 * 8 + kk][f];
    *reinterpret_cast<uint4*>(dst + g8 * 8) = *reinterpret_cast<const uint4*>(o);
  }
}

// ---------------------------------------------------------------------------
// Fused projection GEMM: Y = Wall · xT^T per batch, + bias + PReLU + LN(d,f)
// + affine, writes qf/kf/vf bf16. Tile 128x128, K=128 (2 steps of 64).
// m-tiles: 0,1 = q (2 heads each); 2,3 = k; 4 = v (4 heads).
__global__ __launch_bounds__(256) void proj_gemm_kernel(
    const unsigned short* __restrict__ Wall, const unsigned short* __restrict__ xT,
    const float* __restrict__ ball, const float* __restrict__ aall,
    const float* __restrict__ lwall, const float* __restrict__ lball,
    unsigned short* __restrict__ qf, unsigned short* __restrict__ kf,
    unsigned short* __restrict__ vf) {
  __shared__ alignas(16) unsigned short As[128 * 64];
  __shared__ alignas(16) unsigned short Bs[128 * 64];
  __shared__ float part[4][2][2];

  int p = blockIdx.x;
  int cpx = gridDim.x >> 3;
  int v = (p & 7) * cpx + (p >> 3);
  int bb = v / 2560;
  int tl = v - bb * 2560;
  int tm = tl / 512;
  int t = tl - tm * 512;

  int tid = threadIdx.x;
  int w = tid >> 6, lane = tid & 63;
  int wr = w >> 1, wc = w & 1;
  int lr = lane & 15, kg = lane >> 4;

  const unsigned short* Ab = Wall + (size_t)tm * 128 * 128;
  const unsigned short* Bb = xT + ((size_t)bb * 65536 + (size_t)t * 128) * 128;

  f32x4 acc[4][4] = {};
  for (int k0 = 0; k0 < 128; k0 += 64) {
#pragma unroll
    for (int j = 0; j < 4; ++j) {
      int ch = j * 256 + tid;
      int r = ch >> 3;
      int c = (ch & 7) * 8;
      gl_lds16(Ab + (size_t)r * 128 + k0 + c, &As[ch * 8]);
      gl_lds16(Bb + (size_t)r * 128 + k0 + c, &Bs[ch * 8]);
    }
    __syncthreads();
#pragma unroll
    for (int ks = 0; ks < 2; ++ks) {
      bf16x8 af[4], bf[4];
#pragma unroll
      for (int m = 0; m < 4; ++m)
        af[m] = *reinterpret_cast<const bf16x8*>(
            &As[(wr * 64 + m * 16 + lr) * 64 + ks * 32 + kg * 8]);
#pragma unroll
      for (int n = 0; n < 4; ++n)
        bf[n] = *reinterpret_cast<const bf16x8*>(
            &Bs[(wc * 64 + n * 16 + lr) * 64 + ks * 32 + kg * 8]);
#pragma unroll
      for (int m = 0; m < 4; ++m)
#pragma unroll
        for (int n = 0; n < 4; ++n)
          acc[m][n] = __builtin_amdgcn_mfma_f32_16x16x32_bf16(af[m], bf[n], acc[m][n], 0, 0, 0);
    }
    __syncthreads();
  }

  int sec = (tm < 2) ? 0 : (tm < 4 ? 1 : 2);
  // bias + PReLU + per-group stats
  float s[2] = {0.f, 0.f}, s2[2] = {0.f, 0.f};
#pragma unroll
  for (int m = 0; m < 4; ++m) {
    int g = (sec == 2) ? (m >> 1) : 0;
#pragma unroll
    for (int j = 0; j < 4; ++j) {
      int gm = tm * 128 + wr * 64 + m * 16 + kg * 4 + j;
      float bi = ball[gm];
      float al = aall[gm];
#pragma unroll
      for (int n = 0; n < 4; ++n) {
        float val = acc[m][n][j] + bi;
        val = val >= 0.f ? val : al * val;
        acc[m][n][j] = val;
        s[g] += val;
        s2[g] += val * val;
      }
    }
  }
#pragma unroll
  for (int off = 32; off >= 1; off >>= 1) {
    s[0] += __shfl_xor(s[0], off, 64);
    s2[0] += __shfl_xor(s2[0], off, 64);
    s[1] += __shfl_xor(s[1], off, 64);
    s2[1] += __shfl_xor(s2[1], off, 64);
  }
  if (lane == 0) {
    part[w][0][0] = s[0]; part[w][0][1] = s2[0];
    part[w][1][0] = s[1]; part[w][1][1] = s2[1];
  }
  __syncthreads();
  float invN = (sec == 2) ? (1.f / 4096.f) : (1.f / 8192.f);
  float mu[2], rs[2];
#pragma unroll
  for (int g = 0; g < 2; ++g) {
    float S = part[2 * wr][g][0] + part[2 * wr + 1][g][0];
    float S2 = part[2 * wr][g][1] + part[2 * wr + 1][g][1];
    float m_ = S * invN;
    float var = S2 * invN - m_ * m_;
    mu[g] = m_;
    rs[g] = rsqrtf(var + EPS);
  }
  // affine + write
#pragma unroll
  for (int m = 0; m < 4; ++m) {
    int g = (sec == 2) ? (m >> 1) : 0;
#pragma unroll
    for (int j = 0; j < 4; ++j) {
      int row = wr * 64 + m * 16 + kg * 4 + j;
      int gm = tm * 128 + row;
      const float* lwr = lwall + (size_t)gm * 128;
      const float* lbr = lball + (size_t)gm * 128;
      unsigned short* dst;
      if (sec == 0) {
        int h = gm >> 6, d = gm & 63;
        dst = qf + (((size_t)bb * H + h) * T + t) * E + d * 128;
      } else if (sec == 1) {
        int hm = gm - 256, h = hm >> 6, d = hm & 63;
        dst = kf + (((size_t)bb * H + h) * T + t) * E + d * 128;
      } else {
        int hm = gm - 512, h = hm >> 5, d = hm & 31;
        dst = vf + (((size_t)bb * H + h) * T + t) * EV + d * 128;
      }
#pragma unroll
      for (int n = 0; n < 4; ++n) {
        int f = wc * 64 + n * 16 + lr;
        float val = (acc[m][n][j] - mu[g]) * rs[g] * lwr[f] + lbr[f];
        dst[f] = f2bf(val);
      }
    }
  }
}

// ---------------------------------------------------------------------------
// MFMA GEMM, A·B^T form (unchanged, verified round 2)
template <bool OUT_BF16>
__global__ __launch_bounds__(256) void gemm_bt_kernel(
    const unsigned short* __restrict__ A, const unsigned short* __restrict__ Bm,
    void* __restrict__ Out, int M, int N, int K, float scale, int tiles_m, int tiles_n) {
  __shared__ alignas(16) unsigned short As[128 * 64];
  __shared__ alignas(16) unsigned short Bs[128 * 64];

  int p = blockIdx.x;
  int cpx = gridDim.x >> 3;
  int v = (p & 7) * cpx + (p >> 3);
  int tpb = tiles_m * tiles_n;
  int bh = v / tpb;
  int tl = v - bh * tpb;
  int tm = tl / tiles_n;
  int tn = tl - tm * tiles_n;

  int tid = threadIdx.x;
  int w = tid >> 6, lane = tid & 63;
  int wr = w >> 1, wc = w & 1;
  int lr = lane & 15, kg = lane >> 4;

  const unsigned short* Ab = A + ((size_t)bh * M + tm * 128) * K;
  const unsigned short* Bb = Bm + ((size_t)bh * N + tn * 128) * K;

  f32x4 acc[4][4] = {};
  for (int k0 = 0; k0 < K; k0 += 64) {
#pragma unroll
    for (int j = 0; j < 4; ++j) {
      int ch = j * 256 + tid;
      int r = ch >> 3;
      int c = (ch & 7) * 8;
      gl_lds16(Ab + (size_t)r * K + k0 + c, &As[ch * 8]);
      gl_lds16(Bb + (size_t)r * K + k0 + c, &Bs[ch * 8]);
    }
    __syncthreads();
#pragma unroll
    for (int ks = 0; ks < 2; ++ks) {
      bf16x8 af[4], bf[4];
#pragma unroll
      for (int m = 0; m < 4; ++m)
        af[m] = *reinterpret_cast<const bf16x8*>(
            &As[(wr * 64 + m * 16 + lr) * 64 + ks * 32 + kg * 8]);
#pragma unroll
      for (int n = 0; n < 4; ++n)
        bf[n] = *reinterpret_cast<const bf16x8*>(
            &Bs[(wc * 64 + n * 16 + lr) * 64 + ks * 32 + kg * 8]);
#pragma unroll
      for (int m = 0; m < 4; ++m)
#pragma unroll
        for (int n = 0; n < 4; ++n)
          acc[m][n] = __builtin_amdgcn_mfma_f32_16x16x32_bf16(af[m], bf[n], acc[m][n], 0, 0, 0);
    }
    __syncthreads();
  }

  int orow = tm * 128 + wr * 64 + kg * 4;
  int ocol = tn * 128 + wc * 64 + lr;
  if constexpr (OUT_BF16) {
    unsigned short* O = (unsigned short*)Out + (size_t)bh * M * N;
#pragma unroll
    for (int m = 0; m < 4; ++m)
#pragma unroll
      for (int j = 0; j < 4; ++j) {
        size_t base = (size_t)(orow + m * 16 + j) * N + ocol;
#pragma unroll
        for (int n = 0; n < 4; ++n)
          O[base + n * 16] = f2bf(acc[m][n][j] * scale);
      }
  } else {
    float* O = (float*)Out + (size_t)bh * M * N;
#pragma unroll
    for (int m = 0; m < 4; ++m)
#pragma unroll
      for (int j = 0; j < 4; ++j) {
        size_t base = (size_t)(orow + m * 16 + j) * N + ocol;
#pragma unroll
        for (int n = 0; n < 4; ++n)
          O[base + n * 16] = acc[m][n][j] * scale;
      }
  }
}

// ---------------------------------------------------------------------------
// Transpose vf [bh][T][EV] -> vfT [bh][EV][T] (bf16), 64x64 tiles
__global__ __launch_bounds__(256) void transpose_v_kernel(
    const unsigned short* __restrict__ src, unsigned short* __restrict__ dst) {
  __shared__ unsigned short tile[64][72];
  int bx = blockIdx.x;
  int et = bx & 63;
  int tt = (bx >> 6) & 7;
  int bh = bx >> 9;
  const unsigned short* sb = src + ((size_t)bh * T + tt * 64) * EV + et * 64;
#pragma unroll
  for (int j = 0; j < 2; ++j) {
    int ch = j * 256 + threadIdx.x;
    int r = ch >> 3;
    int c8 = ch & 7;
    uint4 u = *reinterpret_cast<const uint4*>(sb + (size_t)r * EV + c8 * 8);
    *reinterpret_cast<uint4*>(&tile[r][c8 * 8]) = u;
  }
  __syncthreads();
  unsigned short* db = dst + ((size_t)bh * EV + et * 64) * T + tt * 64;
#pragma unroll
  for (int j = 0; j < 2; ++j) {
    int ch = j * 256 + threadIdx.x;
    int r = ch >> 3;
    int c8 = ch & 7;
    unsigned short o[8];
#pragma unroll
    for (int i = 0; i < 8; ++i) o[i] = tile[c8 * 8 + i][r];
    *reinterpret_cast<uint4*>(db + (size_t)r * T + c8 * 8) =
        *reinterpret_cast<const uint4*>(o);
  }
}

// ---------------------------------------------------------------------------
// Softmax over last dim (512); fp32 logits -> bf16 probs
__global__ __launch_bounds__(64) void softmax_kernel(const float* __restrict__ a,
                                                     unsigned short* __restrict__ ob) {
  const float* pr = a + (size_t)blockIdx.x * T;
  int tid = threadIdx.x;
  float4 v0 = *reinterpret_cast<const float4*>(pr + tid * 8);
  float4 v1 = *reinterpret_cast<const float4*>(pr + tid * 8 + 4);
  float mx = fmaxf(fmaxf(fmaxf(v0.x, v0.y), fmaxf(v0.z, v0.w)),
                   fmaxf(fmaxf(v1.x, v1.y), fmaxf(v1.z, v1.w)));
#pragma unroll
  for (int off = 32; off >= 1; off >>= 1) mx = fmaxf(mx, __shfl_xor(mx, off, 64));
  v0.x = __expf(v0.x - mx); v0.y = __expf(v0.y - mx);
  v0.z = __expf(v0.z - mx); v0.w = __expf(v0.w - mx);
  v1.x = __expf(v1.x - mx); v1.y = __expf(v1.y - mx);
  v1.z = __expf(v1.z - mx); v1.w = __expf(v1.w - mx);
  float sm = v0.x + v0.y + v0.z + v0.w + v1.x + v1.y + v1.z + v1.w;
#pragma unroll
  for (int off = 32; off >= 1; off >>= 1) sm += __shfl_xor(sm, off, 64);
  float r = 1.0f / sm;
  uint4 o;
  o.x = (unsigned int)f2bf(v0.x * r) | ((unsigned int)f2bf(v0.y * r) << 16);
  o.y = (unsigned int)f2bf(v0.z * r) | ((unsigned int)f2bf(v0.w * r) << 16);
  o.z = (unsigned int)f2bf(v1.x * r) | ((unsigned int)f2bf(v1.y * r) << 16);
  o.w = (unsigned int)f2bf(v1.z * r) | ((unsigned int)f2bf(v1.w * r) << 16);
  *reinterpret_cast<uint4*>(ob + (size_t)blockIdx.x * T + tid * 8) = o;
}

// ---------------------------------------------------------------------------
// pv [b][h][t][dv*128+f] -> rT [b][(t*128+f)][(h*32+dv)]   one block per (b,t)
__global__ __launch_bounds__(256) void pv2rT_kernel(const unsigned short* __restrict__ pv,
                                                    unsigned short* __restrict__ rT) {
  __shared__ unsigned short tile[128][136];  // [c=h*32+dv][f]
  int bx = blockIdx.x;
  int t = bx & 511;
  int b = bx >> 9;
  int tid = threadIdx.x;
#pragma unroll
  for (int j = 0; j < 8; ++j) {
    int ch = j * 256 + tid;  // 2048 chunks of 8 bf16
    int c = ch >> 4;
    int fc = ch & 15;
    int h = c >> 5, dv = c & 31;
    uint4 u = *reinterpret_cast<const uint4*>(
        pv + (((size_t)b * H + h) * T + t) * EV + dv * 128 + fc * 8);
    *reinterpret_cast<uint4*>(&tile[c][fc * 8]) = u;
  }
  __syncthreads();
  int f = tid >> 1, half = tid & 1;
  unsigned short* dst = rT + ((size_t)b * 65536 + (size_t)t * 128 + f) * 128 + half * 64;
#pragma unroll
  for (int g8 = 0; g8 < 8; ++g8) {
    unsigned short o[8];
#pragma unroll
    for (int kk = 0; kk < 8; ++kk) o[kk] = tile[half * 64 + g8 * 8 + kk][f];
    *reinterpret_cast<uint4*>(dst + g8 * 8) = *reinterpret_cast<const uint4*>(o);
  }
}

// ---------------------------------------------------------------------------
// Fused out-projection: Z = Wo2 · rT^T per (b,t) tile + bias + PReLU +
// LN(C,F) + affine + residual -> fp32 out. Tile = full 128x128 LN group.
__global__ __launch_bounds__(256) void outproj_gemm_kernel(
    const unsigned short* __restrict__ Wo2, const unsigned short* __restrict__ rT,
    const float* __restrict__ bo, const float* __restrict__ ao,
    const float* __restrict__ lwo, const float* __restrict__ lbo,
    const float* __restrict__ x, float* __restrict__ outp) {
  __shared__ alignas(16) unsigned short As[128 * 64];
  __shared__ alignas(16) unsigned short Bs[128 * 64];
  __shared__ float part[4][2];

  int p = blockIdx.x;
  int cpx = gridDim.x >> 3;
  int v = (p & 7) * cpx + (p >> 3);
  int bb = v >> 9;
  int t = v & 511;

  int tid = threadIdx.x;
  int w = tid >> 6, lane = tid & 63;
  int wr = w >> 1, wc = w & 1;
  int lr = lane & 15, kg = lane >> 4;

  const unsigned short* Bb = rT + ((size_t)bb * 65536 + (size_t)t * 128) * 128;

  f32x4 acc[4][4] = {};
  for (int k0 = 0; k0 < 128; k0 += 64) {
#pragma unroll
    for (int j = 0; j < 4; ++j) {
      int ch = j * 256 + tid;
      int r = ch >> 3;
      int c = (ch & 7) * 8;
      gl_lds16(Wo2 + (size_t)r * 128 + k0 + c, &As[ch * 8]);
      gl_lds16(Bb + (size_t)r * 128 + k0 + c, &Bs[ch * 8]);
    }
    __syncthreads();
#pragma unroll
    for (int ks = 0; ks < 2; ++ks) {
      bf16x8 af[4], bf[4];
#pragma unroll
      for (int m = 0; m < 4; ++m)
        af[m] = *reinterpret_cast<const bf16x8*>(
            &As[(wr * 64 + m * 16 + lr) * 64 + ks * 32 + kg * 8]);
#pragma unroll
      for (int n = 0; n < 4; ++n)
        bf[n] = *reinterpret_cast<const bf16x8*>(
            &Bs[(wc * 64 + n * 16 + lr) * 64 + ks * 32 + kg * 8]);
#pragma unroll
      for (int m = 0; m < 4; ++m)
#pragma unroll
        for (int n = 0; n < 4; ++n)
          acc[m][n] = __builtin_amdgcn_mfma_f32_16x16x32_bf16(af[m], bf[n], acc[m][n], 0, 0, 0);
    }
    __syncthreads();
  }

  float aO = ao[0];
  float s = 0.f, s2 = 0.f;
#pragma unroll
  for (int m = 0; m < 4; ++m)
#pragma unroll
    for (int j = 0; j < 4; ++j) {
      int d = wr * 64 + m * 16 + kg * 4 + j;
      float bi = bo[d];
#pragma unroll
      for (int n = 0; n < 4; ++n) {
        float val = acc[m][n][j] + bi;
        val = val >= 0.f ? val : aO * val;
        acc[m][n][j] = val;
        s += val;
        s2 += val * val;
      }
    }
#pragma unroll
  for (int off = 32; off >= 1; off >>= 1) {
    s += __shfl_xor(s, off, 64);
    s2 += __shfl_xor(s2, off, 64);
  }
  if (lane == 0) { part[w][0] = s; part[w][1] = s2; }
  __syncthreads();
  float S = part[0][0] + part[1][0] + part[2][0] + part[3][0];
  float S2 = part[0][1] + part[1][1] + part[2][1] + part[3][1];
  const float invN = 1.f / 16384.f;
  float mu = S * invN;
  float var = S2 * invN - mu * mu;
  float rstd = rsqrtf(var + EPS);
#pragma unroll
  for (int m = 0; m < 4; ++m)
#pragma unroll
    for (int j = 0; j < 4; ++j) {
      int d = wr * 64 + m * 16 + kg * 4 + j;
#pragma unroll
      for (int n = 0; n < 4; ++n) {
        int f = wc * 64 + n * 16 + lr;
        float val = (acc[m][n][j] - mu) * rstd * lwo[d * 128 + f] + lbo[d * 128 + f];
        size_t xi = (((size_t)bb * C + d) * T + t) * F + f;
        outp[xi] = val + x[xi];
      }
    }
}

// ---------------------------------------------------------------------------
extern "C" void kernel_launch(void* const* d_in, const int* in_sizes, int n_in,
                              void* d_out, int out_size, void* d_ws, size_t ws_size,
                              hipStream_t stream) {
  const float* x   = (const float*)d_in[0];
  const float* Wq  = (const float*)d_in[1];
  const float* bq  = (const float*)d_in[2];
  const float* aq  = (const float*)d_in[3];
  const float* lwq = (const float*)d_in[4];
  const float* lbq = (const float*)d_in[5];
  const float* Wk  = (const float*)d_in[6];
  const float* bk_ = (const float*)d_in[7];
  const float* ak  = (const float*)d_in[8];
  const float* lwk = (const float*)d_in[9];
  const float* lbk = (const float*)d_in[10];
  const float* Wv  = (const float*)d_in[11];
  const float* bv  = (const float*)d_in[12];
  const float* av  = (const float*)d_in[13];
  const float* lwv = (const float*)d_in[14];
  const float* lbv = (const float*)d_in[15];
  const float* Wo  = (const float*)d_in[16];
  const float* bo  = (const float*)d_in[17];
  const float* ao  = (const float*)d_in[18];
  const float* lwo = (const float*)d_in[19];
  const float* lbo = (const float*)d_in[20];
  float* outp = (float*)d_out;

  char* ws = (char*)d_ws;
  unsigned short* qfp = (unsigned short*)(ws);                  // 128 MB
  unsigned short* kfp = (unsigned short*)(ws + 134217728ull);   // 128 MB
  unsigned short* vfp = (unsigned short*)(ws + 268435456ull);   //  64 MB
  unsigned short* xT  = (unsigned short*)(ws + 335544320ull);   //  64 MB
  float*          atn = (float*)(ws + 335544320ull);            //  16 MB (after xT dead)
  unsigned short* Wall = (unsigned short*)(ws + 402653184ull);  // 160 KB
  unsigned short* Wo2  = (unsigned short*)(ws + 402849792ull);  //  32 KB
  float*          lwall = (float*)(ws + 402915328ull);          // 320 KB
  float*          lball = (float*)(ws + 403243008ull);          // 320 KB
  float*          ball  = (float*)(ws + 403570688ull);          // 2.5 KB
  float*          aall  = (float*)(ws + 403574784ull);          // 2.5 KB
  // phase-2 reuse
  unsigned short* atnb = (unsigned short*)(ws);                 //  8 MB (ex-qf)
  unsigned short* rT   = (unsigned short*)(ws + 8388608ull);    // 64 MB (ex-qf)
  unsigned short* vfT  = (unsigned short*)(ws + 134217728ull);  // 64 MB (ex-kf)
  unsigned short* pvp  = (unsigned short*)(ws + 268435456ull);  // 64 MB (ex-vf)

  prep_kernel<<<320, 256, 0, stream>>>(Wq, Wk, Wv, Wo, bq, bk_, bv, aq, ak, av,
                                       lwq, lwk, lwv, lbq, lbk, lbv,
                                       Wall, Wo2, ball, aall, lwall, lball);

  xT_kernel<<<2048, 256, 0, stream>>>(x, xT);

  proj_gemm_kernel<<<10240, 256, 0, stream>>>(Wall, xT, ball, aall, lwall, lball,
                                              qfp, kfp, vfp);

  // logits: S = scale * Q K^T  (M=N=512, K=8192), fp32 out (overlays dead xT)
  gemm_bt_kernel<false><<<256, 256, 0, stream>>>(
      qfp, kfp, atn, 512, 512, 8192, 0.011048543456039806f, 4, 4);

  // vf -> vfT (into ex-kf; kf dead after logits)
  transpose_v_kernel<<<8192, 256, 0, stream>>>(vfp, vfT);

  // softmax fp32 -> bf16 probs (into ex-qf)
  softmax_kernel<<<8192, 64, 0, stream>>>(atn, atnb);

  // PV: O = P V  (M=512, N=4096, K=512), bf16 out
  gemm_bt_kernel<true><<<2048, 256, 0, stream>>>(
      atnb, vfT, pvp, 512, 4096, 512, 1.0f, 4, 32);

  // pv -> rT (concat-heads transposed layout)
  pv2rT_kernel<<<2048, 256, 0, stream>>>(pvp, rT);

  outproj_gemm_kernel<<<2048, 256, 0, stream>>>(Wo2, rT, bo, ao, lwo, lbo, x, outp);
}